// Round 4
// baseline (29769.763 us; speedup 1.0000x reference)
//
#include <hip/hip_runtime.h>
#include <math.h>

// ---------------------------------------------------------------------------
// Seq2Seq forward. V=50000 E=H=512 Lin=400 Tout=100 B=64 Lmax=400.
// R9: hoist the output GEMM+loss OUT of the sequential decoder loop.
//  - k_dec2: persistent, 64 blocks, 2 gridbars/step. Phase AB = attn scores +
//    softmax + combine per batch row (one block per row, no inter-block dep).
//    Phase C = GRU (blocks 0..31, verified MFMA tiles), h kept in-place f32 +
//    appended bf16 into Hall[100][64][512].
//  - k_outbatch: AFTER the loop, one normal launch (100 t x 8 vocab slices),
//    MFMA out-GEMM + per-thread online LSE partials. No barriers.
//  - k_lossfinal merges partials -> loss.
// Workspace: Hall replaces per-step pm/ps; out_W bf16 partially pre-converted
// (first 640 of 782 chunks fit), f32+convert tail.
// ---------------------------------------------------------------------------

typedef __attribute__((ext_vector_type(8))) short bh8;   // 8 x bf16 = 4 VGPR
typedef __attribute__((ext_vector_type(4))) float fv4;

#define NSL 8          // vocab slices in k_outbatch
#define CONVCH 640     // chunks of out_W pre-converted to bf16

__device__ __forceinline__ float b2f(short u) {
    union { unsigned int i; float f; } c;
    c.i = ((unsigned int)(unsigned short)u) << 16;
    return c.f;
}
__device__ __forceinline__ short f2b(float f) {
    union { float f; unsigned int u; } c;
    c.f = f;
    unsigned int r = (c.u + 0x7fffu + ((c.u >> 16) & 1u)) >> 16;
    return (short)r;
}
__device__ __forceinline__ bh8 ld8(const float* __restrict__ p) {
    bh8 r;
    #pragma unroll
    for (int j = 0; j < 8; ++j) r[j] = f2b(p[j]);
    return r;
}
__device__ __forceinline__ float sigmf(float x) { return 1.f / (1.f + expf(-x)); }

__device__ __forceinline__ fv4 mfma16(bh8 a, bh8 b, fv4 c) {
    return __builtin_amdgcn_mfma_f32_16x16x32_bf16(a, b, c, 0, 0, 0);
}

// Grid barrier v2 (R8-verified): release add on arrive; poll via RELAXED RMW
// (coherence-point read, no cache maintenance); single acquire fence on exit.
__device__ __forceinline__ void gridbar(unsigned int* bar, unsigned int target) {
    __syncthreads();
    if (threadIdx.x == 0) {
        __hip_atomic_fetch_add(bar, 1u, __ATOMIC_RELEASE, __HIP_MEMORY_SCOPE_AGENT);
        while (__hip_atomic_fetch_add(bar, 0u, __ATOMIC_RELAXED,
                                      __HIP_MEMORY_SCOPE_AGENT) < target) {
            __builtin_amdgcn_s_sleep(16);
        }
        __builtin_amdgcn_fence(__ATOMIC_ACQUIRE, "agent");
    }
    __syncthreads();
}

// f32 -> bf16 bulk convert (n multiple of 4; grid = n/1024 blocks)
__global__ __launch_bounds__(256) void k_cvt(
    const float* __restrict__ s, short* __restrict__ d, int n)
{
    const int i = (blockIdx.x * 256 + threadIdx.x) * 4;
    if (i + 3 < n) {
        fv4 v = *(const fv4*)(s + i);
        short4 o;
        o.x = f2b(v[0]); o.y = f2b(v[1]); o.z = f2b(v[2]); o.w = f2b(v[3]);
        *(short4*)(d + i) = o;
    }
}

// ---------------------------------------------------------------------------
// Persistent encoder: all 400 GRU steps in one launch. 32 blocks x 256 thr.
// (unchanged structure; buffers passed in)
// ---------------------------------------------------------------------------
__global__ __launch_bounds__(256) void k_enc_persist(
    const float* __restrict__ emb, const int* __restrict__ input_t,
    const short* __restrict__ Wb,
    const float* __restrict__ Wih_f, const float* __restrict__ Whh_f,
    const float* __restrict__ bih, const float* __restrict__ bhh,
    float* __restrict__ h_f32, short* __restrict__ h_bf,
    float* __restrict__ enc0, unsigned int* __restrict__ bar)
{
    const int tid  = threadIdx.x;
    const int lane = tid & 63;
    const int wv   = tid >> 6;
    const int n0   = blockIdx.x * 16;
    const int b0   = wv * 16;
    const int l15  = lane & 15;
    const int ko   = lane >> 4;
    const int koff = ko * 8;
    const int brow = b0 + l15;
    const int n    = n0 + l15;

    for (int i = blockIdx.x * 256 + tid; i < 64 * 512; i += 32 * 256) {
        h_f32[i] = 0.f; h_bf[i] = 0;
    }
    gridbar(bar, 32u);

    const bh8 *Wrb = nullptr, *Wzb = nullptr, *Wnb = nullptr;
    const bh8 *Urb = nullptr, *Uzb = nullptr, *Unb = nullptr;
    const float *Wrf = nullptr, *Wzf = nullptr, *Wnf = nullptr;
    const float *Urf = nullptr, *Uzf = nullptr, *Unf = nullptr;
    if (Wb) {
        Wrb = (const bh8*)(Wb + (long long)(n + 0)    * 512) + ko;
        Wzb = (const bh8*)(Wb + (long long)(n + 512)  * 512) + ko;
        Wnb = (const bh8*)(Wb + (long long)(n + 1024) * 512) + ko;
        Urb = (const bh8*)(Wb + (long long)(n + 1536) * 512) + ko;
        Uzb = (const bh8*)(Wb + (long long)(n + 2048) * 512) + ko;
        Unb = (const bh8*)(Wb + (long long)(n + 2560) * 512) + ko;
    } else {
        Wrf = Wih_f + (long long)(n + 0)    * 512 + koff;
        Wzf = Wih_f + (long long)(n + 512)  * 512 + koff;
        Wnf = Wih_f + (long long)(n + 1024) * 512 + koff;
        Urf = Whh_f + (long long)(n + 0)    * 512 + koff;
        Uzf = Whh_f + (long long)(n + 512)  * 512 + koff;
        Unf = Whh_f + (long long)(n + 1024) * 512 + koff;
    }
    const float bir = bih[n], biz = bih[n + 512], bin = bih[n + 1024];
    const float bhr = bhh[n], bhz = bhh[n + 512], bhn = bhh[n + 1024];

    for (int t = 0; t < 400; ++t) {
        const float* hi  = h_f32 + (t & 1) * 32768;
        const short* hib = h_bf  + (t & 1) * 32768;
        float* ho  = h_f32 + ((t + 1) & 1) * 32768;
        short* hob = h_bf  + ((t + 1) & 1) * 32768;

        const int tok = input_t[t * 64 + brow];
        const float* Ap = emb + (long long)tok * 512 + koff;
        const bh8*  Hp  = (const bh8*)(hib + (long long)brow * 512) + ko;

        fv4 air = {0.f, 0.f, 0.f, 0.f};
        fv4 aiz = air, ain = air, ahr = air, ahz = air, ahn = air;
        if (Wb) {
            #pragma unroll 4
            for (int kk = 0; kk < 16; ++kk) {
                const bh8 a = ld8(Ap + kk * 32);
                const bh8 h = Hp[kk * 4];
                air = mfma16(a, Wrb[kk * 4], air);
                aiz = mfma16(a, Wzb[kk * 4], aiz);
                ain = mfma16(a, Wnb[kk * 4], ain);
                ahr = mfma16(h, Urb[kk * 4], ahr);
                ahz = mfma16(h, Uzb[kk * 4], ahz);
                ahn = mfma16(h, Unb[kk * 4], ahn);
            }
        } else {
            #pragma unroll 4
            for (int kk = 0; kk < 16; ++kk) {
                const bh8 a = ld8(Ap + kk * 32);
                const bh8 h = Hp[kk * 4];
                air = mfma16(a, ld8(Wrf + kk * 32), air);
                aiz = mfma16(a, ld8(Wzf + kk * 32), aiz);
                ain = mfma16(a, ld8(Wnf + kk * 32), ain);
                ahr = mfma16(h, ld8(Urf + kk * 32), ahr);
                ahz = mfma16(h, ld8(Uzf + kk * 32), ahz);
                ahn = mfma16(h, ld8(Unf + kk * 32), ahn);
            }
        }
        #pragma unroll
        for (int r = 0; r < 4; ++r) {
            const int b = b0 + ko * 4 + r;
            const float rr = sigmf(air[r] + bir + ahr[r] + bhr);
            const float zz = sigmf(aiz[r] + biz + ahz[r] + bhz);
            const float nn = tanhf(ain[r] + bin + rr * (ahn[r] + bhn));
            const float hold = hi[b * 512 + n];
            const float hnew = (1.f - zz) * nn + zz * hold;
            ho[b * 512 + n] = hnew;
            hob[b * 512 + n] = f2b(hnew);
            if (t == 0) enc0[b * 512 + n] = hnew;
        }
        gridbar(bar, 32u * (t + 2));
    }
}

// ---------------------------------------------------------------------------
// Persistent recurrent decoder (no output GEMM): 64 blocks x 256 threads.
// Per step: Phase AB (block r: scores->softmax->combine) | bar |
//           Phase C (blocks 0..31: GRU -> h f32 in-place + Hall[t] bf16) | bar.
// ---------------------------------------------------------------------------
__global__ __launch_bounds__(256) void k_dec2(
    const float* __restrict__ emb, const float* __restrict__ enc0,
    const float* __restrict__ attn_W, const float* __restrict__ attn_b,
    const float* __restrict__ comb_W, const float* __restrict__ comb_b,
    const short* __restrict__ decWb,
    const float* __restrict__ dec_Wih, const float* __restrict__ dec_Whh,
    const float* __restrict__ dec_bih, const float* __restrict__ dec_bhh,
    const int* __restrict__ target,
    float* __restrict__ h,          // [64][512] f32 (in-place state)
    const float* __restrict__ h0,   // encoder final h f32
    const short* __restrict__ h0b,  // encoder final h bf16
    short* __restrict__ c_bf, short* __restrict__ Hall,
    unsigned int* __restrict__ bar2)
{
    __shared__ __align__(16) float sx[1024];
    __shared__ float sc[400];
    __shared__ float red[256];
    __shared__ float a0s;
    const int tid = threadIdx.x;
    const int bid = blockIdx.x;
    unsigned int tgt = 0u;

    for (int t = 0; t < 100; ++t) {
        // ---------------- Phase AB (all 64 blocks, r = bid) ----------------
        {
            const int r = bid;
            const float* hsrc = (t == 0) ? h0 : h;
            const int tok = (t == 0) ? 1 : target[(t - 1) * 64 + r];
            for (int k = tid; k < 512; k += 256) {
                sx[k]       = emb[(long long)tok * 512 + k];
                sx[512 + k] = hsrc[r * 512 + k];
            }
            __syncthreads();
            for (int nn = tid; nn < 400; nn += 256) {
                const fv4* wrow = (const fv4*)(attn_W + (long long)nn * 1024);
                float s0 = 0.f, s1 = 0.f, s2 = 0.f, s3 = 0.f;
                for (int kc = 0; kc < 256; ++kc) {
                    const fv4 v = wrow[kc];
                    const fv4 xv = *(const fv4*)(sx + kc * 4);   // ds_read_b128 broadcast
                    s0 += v[0] * xv[0]; s1 += v[1] * xv[1];
                    s2 += v[2] * xv[2]; s3 += v[3] * xv[3];
                }
                sc[nn] = (s0 + s1) + (s2 + s3) + attn_b[nn];
            }
            __syncthreads();
            float m = -1e30f;
            for (int nn = tid; nn < 400; nn += 256) m = fmaxf(m, sc[nn]);
            red[tid] = m;
            __syncthreads();
            for (int s = 128; s > 0; s >>= 1) {
                if (tid < s) red[tid] = fmaxf(red[tid], red[tid + s]);
                __syncthreads();
            }
            m = red[0];
            __syncthreads();
            float ss = 0.f;
            for (int nn = tid; nn < 400; nn += 256) ss += expf(sc[nn] - m);
            red[tid] = ss;
            __syncthreads();
            for (int s = 128; s > 0; s >>= 1) {
                if (tid < s) red[tid] += red[tid + s];
                __syncthreads();
            }
            if (tid == 0) a0s = expf(sc[0] - m) / red[0];
            __syncthreads();
            const float a0 = a0s;
            for (int k = tid; k < 512; k += 256)
                sx[512 + k] = enc0[r * 512 + k] * a0;
            __syncthreads();
            for (int j = tid; j < 512; j += 256) {
                const fv4* wrow = (const fv4*)(comb_W + (long long)j * 1024);
                float s0 = 0.f, s1 = 0.f, s2 = 0.f, s3 = 0.f;
                for (int kc = 0; kc < 256; ++kc) {
                    const fv4 v = wrow[kc];
                    const fv4 xv = *(const fv4*)(sx + kc * 4);
                    s0 += v[0] * xv[0]; s1 += v[1] * xv[1];
                    s2 += v[2] * xv[2]; s3 += v[3] * xv[3];
                }
                const float acc = (s0 + s1) + (s2 + s3) + comb_b[j];
                c_bf[r * 512 + j] = f2b(fmaxf(acc, 0.f));
            }
        }
        tgt += 64u; gridbar(bar2, tgt);

        // ---------------- Phase C: GRU (blocks 0..31) ----------------
        if (bid < 32) {
            const int lane = tid & 63;
            const int w    = bid * 4 + (tid >> 6);
            const int b0g  = (w & 3) * 16;
            const int n0g  = (w >> 2) * 16;
            const int l15  = lane & 15;
            const int ko   = lane >> 4;
            const int koff = ko * 8;
            const int brow = b0g + l15;
            const int n    = n0g + l15;

            const short* Hprev = (t == 0) ? h0b : (Hall + (long long)(t - 1) * 32768);
            const float* hsrc  = (t == 0) ? h0  : h;
            const bh8* Ap = (const bh8*)(c_bf + (long long)brow * 512) + ko;
            const bh8* Hp = (const bh8*)(Hprev + (long long)brow * 512) + ko;

            fv4 air = {0.f, 0.f, 0.f, 0.f};
            fv4 aiz = air, ain = air, ahr = air, ahz = air, ahn = air;
            if (decWb) {
                const bh8* Wr = (const bh8*)(decWb + (long long)(n + 0)    * 512) + ko;
                const bh8* Wz = (const bh8*)(decWb + (long long)(n + 512)  * 512) + ko;
                const bh8* Wn = (const bh8*)(decWb + (long long)(n + 1024) * 512) + ko;
                const bh8* Ur = (const bh8*)(decWb + (long long)(n + 1536) * 512) + ko;
                const bh8* Uz = (const bh8*)(decWb + (long long)(n + 2048) * 512) + ko;
                const bh8* Un = (const bh8*)(decWb + (long long)(n + 2560) * 512) + ko;
                #pragma unroll 4
                for (int kk = 0; kk < 16; ++kk) {
                    const bh8 a = Ap[kk * 4];
                    const bh8 hh = Hp[kk * 4];
                    air = mfma16(a,  Wr[kk * 4], air);
                    aiz = mfma16(a,  Wz[kk * 4], aiz);
                    ain = mfma16(a,  Wn[kk * 4], ain);
                    ahr = mfma16(hh, Ur[kk * 4], ahr);
                    ahz = mfma16(hh, Uz[kk * 4], ahz);
                    ahn = mfma16(hh, Un[kk * 4], ahn);
                }
            } else {
                const float* Wr = dec_Wih + (long long)(n + 0)    * 512 + koff;
                const float* Wz = dec_Wih + (long long)(n + 512)  * 512 + koff;
                const float* Wn = dec_Wih + (long long)(n + 1024) * 512 + koff;
                const float* Ur = dec_Whh + (long long)(n + 0)    * 512 + koff;
                const float* Uz = dec_Whh + (long long)(n + 512)  * 512 + koff;
                const float* Un = dec_Whh + (long long)(n + 1024) * 512 + koff;
                #pragma unroll 4
                for (int kk = 0; kk < 16; ++kk) {
                    const bh8 a = Ap[kk * 4];
                    const bh8 hh = Hp[kk * 4];
                    air = mfma16(a,  ld8(Wr + kk * 32), air);
                    aiz = mfma16(a,  ld8(Wz + kk * 32), aiz);
                    ain = mfma16(a,  ld8(Wn + kk * 32), ain);
                    ahr = mfma16(hh, ld8(Ur + kk * 32), ahr);
                    ahz = mfma16(hh, ld8(Uz + kk * 32), ahz);
                    ahn = mfma16(hh, ld8(Un + kk * 32), ahn);
                }
            }
            const float bir = dec_bih[n], biz = dec_bih[n + 512], bin = dec_bih[n + 1024];
            const float bhr = dec_bhh[n], bhz = dec_bhh[n + 512], bhn = dec_bhh[n + 1024];
            short* Ht = Hall + (long long)t * 32768;
            #pragma unroll
            for (int rr = 0; rr < 4; ++rr) {
                const int b = b0g + ko * 4 + rr;
                const float rg = sigmf(air[rr] + bir + ahr[rr] + bhr);
                const float zg = sigmf(aiz[rr] + biz + ahz[rr] + bhz);
                const float ng = tanhf(ain[rr] + bin + rg * (ahn[rr] + bhn));
                const float hold = hsrc[b * 512 + n];
                const float hnew = (1.f - zg) * ng + zg * hold;
                h[b * 512 + n] = hnew;
                Ht[b * 512 + n] = f2b(hnew);
            }
        }
        tgt += 64u; gridbar(bar2, tgt);
    }
}

// ---------------------------------------------------------------------------
// Batched output GEMM + online-LSE partials. Grid = 100 t x NSL slices.
// slice = bid & 7 (-> XCD-aligned under round-robin), t = bid >> 3.
// Per (t,s): stream 98 chunks of 64 vocab; MFMA layout = verified k_outloss;
// per-thread (row, 16-col seg) online LSE across chunks; 4-seg merge at end.
// ---------------------------------------------------------------------------
__global__ __launch_bounds__(256) void k_outbatch(
    const short* __restrict__ Hall,
    const short* __restrict__ outWb, const float* __restrict__ outW,
    const float* __restrict__ outb, const int* __restrict__ target,
    float* __restrict__ pm2, float* __restrict__ ps2, float* __restrict__ tlog2)
{
    __shared__ float sl[64][65];
    __shared__ float mm[4][64], sm[4][64], tm[4][64];
    const int tid  = threadIdx.x;
    const int s    = blockIdx.x & 7;
    const int t    = blockIdx.x >> 3;
    const int lane = tid & 63;
    const int wl   = tid >> 6;
    const int l15  = lane & 15;
    const int ko   = lane >> 4;
    const short* Ht = Hall + (long long)t * 32768;
    const bh8* A0 = (const bh8*)(Ht + (long long)(0  + l15) * 512) + ko;
    const bh8* A1 = (const bh8*)(Ht + (long long)(16 + l15) * 512) + ko;
    const bh8* A2 = (const bh8*)(Ht + (long long)(32 + l15) * 512) + ko;
    const bh8* A3 = (const bh8*)(Ht + (long long)(48 + l15) * 512) + ko;

    const int row = tid & 63;
    const int seg = tid >> 6;
    const int tg  = target[t * 64 + row];
    float lm = -1e30f, ls = 0.f, tcap = -1e30f;

    const int ch0 = s * 98;
    const int ch1 = (ch0 + 98 < 782) ? (ch0 + 98) : 782;
    for (int ch = ch0; ch < ch1; ++ch) {
        const int base = ch * 64;
        const int n0c  = base + wl * 16;
        const int v    = n0c + l15;
        const int vcl  = (v < 50000) ? v : 49999;
        bh8 bb[16];
        if (outWb && ch < CONVCH) {
            const bh8* Bp = (const bh8*)(outWb + (long long)vcl * 512) + ko;
            #pragma unroll
            for (int kk = 0; kk < 16; ++kk) bb[kk] = Bp[kk * 4];
        } else {
            const float* Bp = outW + (long long)vcl * 512 + ko * 8;
            #pragma unroll
            for (int kk = 0; kk < 16; ++kk) bb[kk] = ld8(Bp + kk * 32);
        }
        fv4 c0 = {0.f, 0.f, 0.f, 0.f};
        fv4 c1 = c0, c2 = c0, c3 = c0;
        #pragma unroll
        for (int kk = 0; kk < 16; ++kk) {
            c0 = mfma16(A0[kk * 4], bb[kk], c0);
            c1 = mfma16(A1[kk * 4], bb[kk], c1);
            c2 = mfma16(A2[kk * 4], bb[kk], c2);
            c3 = mfma16(A3[kk * 4], bb[kk], c3);
        }
        const float bv = outb[vcl];
        const int cc = wl * 16 + l15;
        const bool ok = (v < 50000);
        #pragma unroll
        for (int rr = 0; rr < 4; ++rr) {
            const int rw = ko * 4 + rr;
            sl[0  + rw][cc] = ok ? (c0[rr] + bv) : -1e30f;
            sl[16 + rw][cc] = ok ? (c1[rr] + bv) : -1e30f;
            sl[32 + rw][cc] = ok ? (c2[rr] + bv) : -1e30f;
            sl[48 + rw][cc] = ok ? (c3[rr] + bv) : -1e30f;
        }
        __syncthreads();
        #pragma unroll
        for (int j = 0; j < 16; ++j) {
            const float x = sl[row][seg * 16 + j];
            if (x > lm) { ls = ls * expf(lm - x) + 1.f; lm = x; }
            else        { ls += expf(x - lm); }
            if (base + seg * 16 + j == tg) tcap = x;
        }
        __syncthreads();
    }
    mm[seg][row] = lm; sm[seg][row] = ls; tm[seg][row] = tcap;
    __syncthreads();
    if (tid < 64) {
        float M = mm[0][tid], S = sm[0][tid], T = tm[0][tid];
        #pragma unroll
        for (int g = 1; g < 4; ++g) {
            const float m2 = mm[g][tid], s2 = sm[g][tid];
            const float Mx = fmaxf(M, m2);
            S = S * expf(M - Mx) + s2 * expf(m2 - Mx);
            M = Mx;
            T = fmaxf(T, tm[g][tid]);
        }
        pm2[((long long)t * NSL + s) * 64 + tid] = M;
        ps2[((long long)t * NSL + s) * 64 + tid] = S;
        if (T > -5e29f) tlog2[t * 64 + tid] = T;
    }
}

// merge NSL slice partials -> per-(t,b) logprob -> loss sum
__global__ __launch_bounds__(64) void k_lossfinal(
    const float* __restrict__ pm2, const float* __restrict__ ps2,
    const float* __restrict__ tlog2, float* __restrict__ lacc)
{
    __shared__ float rs[64];
    const int t = blockIdx.x;
    const int b = threadIdx.x;
    float M = pm2[((long long)t * NSL) * 64 + b];
    float S = ps2[((long long)t * NSL) * 64 + b];
    for (int g = 1; g < NSL; ++g) {
        const float m2 = pm2[((long long)t * NSL + g) * 64 + b];
        const float s2 = ps2[((long long)t * NSL + g) * 64 + b];
        const float Mx = fmaxf(M, m2);
        S = S * expf(M - Mx) + s2 * expf(m2 - Mx);
        M = Mx;
    }
    const float lp = tlog2[t * 64 + b] - (M + logf(S));
    rs[b] = lp;
    __syncthreads();
    for (int st = 32; st > 0; st >>= 1) {
        if (b < st) rs[b] += rs[b + st];
        __syncthreads();
    }
    if (b == 0) atomicAdd(lacc, -rs[0] * (1.f / 64.f));
}

// ---------------------------------------------------------------------------
// Fallback decoder kernels (tiny-workspace path only; unchanged).
// ---------------------------------------------------------------------------
__global__ __launch_bounds__(256) void k_gru1(
    const short* __restrict__ c_bf, const short* __restrict__ Wb,
    const float* __restrict__ Wih_f, const float* __restrict__ Whh_f,
    const float* __restrict__ bih, const float* __restrict__ bhh,
    const float* __restrict__ hi, const short* __restrict__ hib,
    float* __restrict__ ho, short* __restrict__ hob)
{
    const int tid  = threadIdx.x;
    const int lane = tid & 63;
    const int w    = blockIdx.x * 4 + (tid >> 6);
    const int b0   = (w & 3) * 16;
    const int n0   = (w >> 2) * 16;
    const int l15  = lane & 15;
    const int ko   = lane >> 4;
    const int koff = ko * 8;
    const int brow = b0 + l15;
    const int n    = n0 + l15;

    const bh8* Ap = (const bh8*)(c_bf + (long long)brow * 512) + ko;
    const bh8* Hp = (const bh8*)(hib + (long long)brow * 512) + ko;

    fv4 air = {0.f, 0.f, 0.f, 0.f};
    fv4 aiz = air, ain = air, ahr = air, ahz = air, ahn = air;
    if (Wb) {
        const bh8* Wr = (const bh8*)(Wb + (long long)(n + 0)    * 512) + ko;
        const bh8* Wz = (const bh8*)(Wb + (long long)(n + 512)  * 512) + ko;
        const bh8* Wn = (const bh8*)(Wb + (long long)(n + 1024) * 512) + ko;
        const bh8* Ur = (const bh8*)(Wb + (long long)(n + 1536) * 512) + ko;
        const bh8* Uz = (const bh8*)(Wb + (long long)(n + 2048) * 512) + ko;
        const bh8* Un = (const bh8*)(Wb + (long long)(n + 2560) * 512) + ko;
        #pragma unroll 4
        for (int kk = 0; kk < 16; ++kk) {
            const bh8 a = Ap[kk * 4];
            const bh8 h = Hp[kk * 4];
            air = mfma16(a, Wr[kk * 4], air);
            aiz = mfma16(a, Wz[kk * 4], aiz);
            ain = mfma16(a, Wn[kk * 4], ain);
            ahr = mfma16(h, Ur[kk * 4], ahr);
            ahz = mfma16(h, Uz[kk * 4], ahz);
            ahn = mfma16(h, Un[kk * 4], ahn);
        }
    } else {
        const float* Wr = Wih_f + (long long)(n + 0)    * 512 + koff;
        const float* Wz = Wih_f + (long long)(n + 512)  * 512 + koff;
        const float* Wn = Wih_f + (long long)(n + 1024) * 512 + koff;
        const float* Ur = Whh_f + (long long)(n + 0)    * 512 + koff;
        const float* Uz = Whh_f + (long long)(n + 512)  * 512 + koff;
        const float* Un = Whh_f + (long long)(n + 1024) * 512 + koff;
        #pragma unroll 4
        for (int kk = 0; kk < 16; ++kk) {
            const bh8 a = Ap[kk * 4];
            const bh8 h = Hp[kk * 4];
            air = mfma16(a, ld8(Wr + kk * 32), air);
            aiz = mfma16(a, ld8(Wz + kk * 32), aiz);
            ain = mfma16(a, ld8(Wn + kk * 32), ain);
            ahr = mfma16(h, ld8(Ur + kk * 32), ahr);
            ahz = mfma16(h, ld8(Uz + kk * 32), ahz);
            ahn = mfma16(h, ld8(Un + kk * 32), ahn);
        }
    }
    const float bir = bih[n], biz = bih[n + 512], bin = bih[n + 1024];
    const float bhr = bhh[n], bhz = bhh[n + 512], bhn = bhh[n + 1024];
    #pragma unroll
    for (int r = 0; r < 4; ++r) {
        const int b = b0 + ko * 4 + r;
        const float rr = sigmf(air[r] + bir + ahr[r] + bhr);
        const float zz = sigmf(aiz[r] + biz + ahz[r] + bhz);
        const float nn = tanhf(ain[r] + bin + rr * (ahn[r] + bhn));
        const float hold = hi[b * 512 + n];
        const float hnew = (1.f - zz) * nn + zz * hold;
        ho[b * 512 + n] = hnew;
        hob[b * 512 + n] = f2b(hnew);
    }
}

__global__ __launch_bounds__(256) void k_attncomb(
    const float* __restrict__ emb, const float* __restrict__ h_f32,
    const float* __restrict__ enc0,
    const float* __restrict__ attn_W, const float* __restrict__ attn_b,
    const float* __restrict__ comb_W, const float* __restrict__ comb_b,
    const int* __restrict__ target, int td, short* __restrict__ c_bf)
{
    __shared__ float sx[1024];
    __shared__ float sc[400];
    __shared__ float red[256];
    __shared__ float a0s;
    const int b = blockIdx.x;
    const int tid = threadIdx.x;
    const int tok = (td == 0) ? 1 : target[(td - 1) * 64 + b];
    for (int k = tid; k < 512; k += 256) {
        sx[k] = emb[(long long)tok * 512 + k];
        sx[512 + k] = h_f32[b * 512 + k];
    }
    __syncthreads();
    for (int nn = tid; nn < 400; nn += 256) {
        const fv4* wrow = (const fv4*)(attn_W + (long long)nn * 1024);
        float acc = 0.f;
        for (int kc = 0; kc < 256; ++kc) {
            fv4 v = wrow[kc];
            acc += v[0] * sx[kc * 4 + 0] + v[1] * sx[kc * 4 + 1]
                 + v[2] * sx[kc * 4 + 2] + v[3] * sx[kc * 4 + 3];
        }
        sc[nn] = acc + attn_b[nn];
    }
    __syncthreads();
    float m = -1e30f;
    for (int nn = tid; nn < 400; nn += 256) m = fmaxf(m, sc[nn]);
    red[tid] = m;
    __syncthreads();
    for (int s = 128; s > 0; s >>= 1) {
        if (tid < s) red[tid] = fmaxf(red[tid], red[tid + s]);
        __syncthreads();
    }
    m = red[0];
    __syncthreads();
    float ss = 0.f;
    for (int nn = tid; nn < 400; nn += 256) ss += expf(sc[nn] - m);
    red[tid] = ss;
    __syncthreads();
    for (int s = 128; s > 0; s >>= 1) {
        if (tid < s) red[tid] += red[tid + s];
        __syncthreads();
    }
    if (tid == 0) a0s = expf(sc[0] - m) / red[0];
    __syncthreads();
    const float a0b = a0s;
    for (int k = tid; k < 512; k += 256) sx[512 + k] = enc0[b * 512 + k] * a0b;
    __syncthreads();
    for (int j = tid; j < 512; j += 256) {
        const fv4* wrow = (const fv4*)(comb_W + (long long)j * 1024);
        float acc = 0.f;
        for (int kc = 0; kc < 256; ++kc) {
            fv4 v = wrow[kc];
            acc += v[0] * sx[kc * 4 + 0] + v[1] * sx[kc * 4 + 1]
                 + v[2] * sx[kc * 4 + 2] + v[3] * sx[kc * 4 + 3];
        }
        acc += comb_b[j];
        c_bf[b * 512 + j] = f2b(fmaxf(acc, 0.f));
    }
}

__global__ __launch_bounds__(256) void k_outloss(
    const short* __restrict__ h2bf,
    const short* __restrict__ outWb, const float* __restrict__ outW,
    const float* __restrict__ outb, const int* __restrict__ target,
    float* __restrict__ pm, float* __restrict__ ps, float* __restrict__ tlogit)
{
    __shared__ float sl[64][65];
    const int tid  = threadIdx.x;
    const int lane = tid & 63;
    const int wl   = tid >> 6;
    const int base = blockIdx.x * 64;
    const int n0   = base + wl * 16;
    const int l15  = lane & 15;
    const int ko   = lane >> 4;

    const int v    = n0 + l15;
    const int vcl  = (v < 50000) ? v : 49999;
    const bh8* A0 = (const bh8*)(h2bf + (long long)(0  + l15) * 512) + ko;
    const bh8* A1 = (const bh8*)(h2bf + (long long)(16 + l15) * 512) + ko;
    const bh8* A2 = (const bh8*)(h2bf + (long long)(32 + l15) * 512) + ko;
    const bh8* A3 = (const bh8*)(h2bf + (long long)(48 + l15) * 512) + ko;
    fv4 c0 = {0.f, 0.f, 0.f, 0.f};
    fv4 c1 = c0, c2 = c0, c3 = c0;
    if (outWb) {
        const bh8* Bp = (const bh8*)(outWb + (long long)vcl * 512) + ko;
        #pragma unroll 4
        for (int kk = 0; kk < 16; ++kk) {
            const bh8 bb = Bp[kk * 4];
            c0 = mfma16(A0[kk * 4], bb, c0);
            c1 = mfma16(A1[kk * 4], bb, c1);
            c2 = mfma16(A2[kk * 4], bb, c2);
            c3 = mfma16(A3[kk * 4], bb, c3);
        }
    } else {
        const float* Bp = outW + (long long)vcl * 512 + ko * 8;
        #pragma unroll 4
        for (int kk = 0; kk < 16; ++kk) {
            const bh8 bb = ld8(Bp + kk * 32);
            c0 = mfma16(A0[kk * 4], bb, c0);
            c1 = mfma16(A1[kk * 4], bb, c1);
            c2 = mfma16(A2[kk * 4], bb, c2);
            c3 = mfma16(A3[kk * 4], bb, c3);
        }
    }
    const float bv = outb[vcl];
    const int cc = wl * 16 + l15;
    const bool ok = (v < 50000);
    #pragma unroll
    for (int r = 0; r < 4; ++r) {
        const int row = ko * 4 + r;
        sl[0  + row][cc] = ok ? (c0[r] + bv) : -1e30f;
        sl[16 + row][cc] = ok ? (c1[r] + bv) : -1e30f;
        sl[32 + row][cc] = ok ? (c2[r] + bv) : -1e30f;
        sl[48 + row][cc] = ok ? (c3[r] + bv) : -1e30f;
    }
    __syncthreads();
    if (tid < 64) {
        const int b = tid;
        float m = -1e30f, s = 0.f;
        for (int c = 0; c < 64; ++c) {
            const float x = sl[b][c];
            if (x > m) { s = s * expf(m - x) + 1.f; m = x; }
            else       { s += expf(x - m); }
        }
        pm[blockIdx.x * 64 + b] = m;
        ps[blockIdx.x * 64 + b] = s;
        const int tg = target[b];
        const int rel = tg - base;
        if (rel >= 0 && rel < 64) tlogit[b] = sl[b][rel];
    }
}

__global__ __launch_bounds__(256) void k_lossred(
    const float* __restrict__ pm, const float* __restrict__ ps,
    const float* __restrict__ tlogit, float* __restrict__ loss_acc)
{
    __shared__ float rm[256], rs[256];
    const int b = blockIdx.x;
    const int tid = threadIdx.x;
    float m = -1e30f, s = 0.f;
    for (int i = tid; i < 782; i += 256) {
        const float m2 = pm[i * 64 + b];
        const float s2 = ps[i * 64 + b];
        if (m2 > m) { s = s * expf(m - m2) + s2; m = m2; }
        else        { s += s2 * expf(m2 - m); }
    }
    rm[tid] = m; rs[tid] = s;
    __syncthreads();
    for (int st = 128; st > 0; st >>= 1) {
        if (tid < st) {
            const float m2 = rm[tid + st], s2 = rs[tid + st];
            const float M = fmaxf(rm[tid], m2);
            rs[tid] = rs[tid] * expf(rm[tid] - M) + s2 * expf(m2 - M);
            rm[tid] = M;
        }
        __syncthreads();
    }
    if (tid == 0) {
        const float logp = tlogit[b] - (rm[0] + logf(rs[0]));
        atomicAdd(loss_acc, -logp * (1.f / 64.f));
    }
}

__global__ void k_init(float* loss_acc, unsigned int* bar, unsigned int* bar2)
{
    if (threadIdx.x == 0 && blockIdx.x == 0) {
        *loss_acc = 0.f; *bar = 0u; *bar2 = 0u;
    }
}

__global__ void k_final(const float* loss_acc, float* out)
{
    out[0] = *loss_acc;
}

extern "C" void kernel_launch(void* const* d_in, const int* in_sizes, int n_in,
                              void* d_out, int out_size, void* d_ws, size_t ws_size,
                              hipStream_t stream)
{
    const float* emb     = (const float*)d_in[0];
    const float* enc_Wih = (const float*)d_in[1];
    const float* enc_Whh = (const float*)d_in[2];
    const float* enc_bih = (const float*)d_in[3];
    const float* enc_bhh = (const float*)d_in[4];
    const float* attn_W  = (const float*)d_in[5];
    const float* attn_b  = (const float*)d_in[6];
    const float* comb_W  = (const float*)d_in[7];
    const float* comb_b  = (const float*)d_in[8];
    const float* dec_Wih = (const float*)d_in[9];
    const float* dec_Whh = (const float*)d_in[10];
    const float* dec_bih = (const float*)d_in[11];
    const float* dec_bhh = (const float*)d_in[12];
    const float* out_W   = (const float*)d_in[13];
    const float* out_b   = (const float*)d_in[14];
    const int*   input_t = (const int*)d_in[15];
    const int*   target_t= (const int*)d_in[16];

    char* ws = (char*)d_ws;

    // ---- fused-path workspace map ----
    float* h_f32  = (float*)(ws + 0);          // [64,512] f32 (in-place state)
    float* enc0   = (float*)(ws + 131072);     // [64,512] f32
    short* c_bf   = (short*)(ws + 262144);     // [64,512] bf16
    short* hm1    = (short*)(ws + 327680);     // (unused slot, kept for align)
    float* lacc   = (float*)(ws + 393216);
    unsigned int* bar  = (unsigned int*)(ws + 393472);
    unsigned int* bar2 = (unsigned int*)(ws + 393728);
    float* pm2    = (float*)(ws + 393984);     // [100][8][64]
    float* ps2    = (float*)(ws + 598784);     // [100][8][64]
    float* tlog2  = (float*)(ws + 803584);     // [100][64]
    short* Hall   = (short*)(ws + 829184);     // [100][64][512] bf16 -> 7382784
    float* he_f32 = (float*)(ws + 7382784);    // encoder h, 2 x [64,512] f32
    short* he_bf  = (short*)(ws + 7644928);    // encoder h, 2 x [64,512] bf16
    short* encWb  = (short*)(ws + 7776000);    // 3072x512 bf16
    short* decWb  = (short*)(ws + 10921728);   // 3072x512 bf16
    short* outWb3 = (short*)(ws + 14067456);   // first 640 chunks of out_W bf16
    (void)hm1;

    const bool fuse  = ws_size >= 14067456;                 // map above (sans outWb3)
    const bool tierP = ws_size >= 14067456 + 41943040ull;   // + partial out_W bf16

    if (fuse) {
        k_init<<<1, 64, 0, stream>>>(lacc, bar, bar2);
        k_cvt<<<768, 256, 0, stream>>>(enc_Wih, encWb, 786432);
        k_cvt<<<768, 256, 0, stream>>>(enc_Whh, encWb + 786432, 786432);
        k_cvt<<<768, 256, 0, stream>>>(dec_Wih, decWb, 786432);
        k_cvt<<<768, 256, 0, stream>>>(dec_Whh, decWb + 786432, 786432);
        if (tierP)
            k_cvt<<<20480, 256, 0, stream>>>(out_W, outWb3, 20971520);

        // encoder: persistent, final h lands at parity 0
        k_enc_persist<<<32, 256, 0, stream>>>(
            emb, input_t, encWb, enc_Wih, enc_Whh,
            enc_bih, enc_bhh, he_f32, he_bf, enc0, bar);

        // recurrent decoder: 64 blocks, 2 barriers/step
        k_dec2<<<64, 256, 0, stream>>>(
            emb, enc0, attn_W, attn_b, comb_W, comb_b,
            decWb, dec_Wih, dec_Whh, dec_bih, dec_bhh, target_t,
            h_f32, he_f32, he_bf, c_bf, Hall, bar2);

        // batched output GEMM + LSE partials (no barriers)
        k_outbatch<<<100 * NSL, 256, 0, stream>>>(
            Hall, tierP ? outWb3 : nullptr, out_W, out_b, target_t,
            pm2, ps2, tlog2);
        k_lossfinal<<<100, 64, 0, stream>>>(pm2, ps2, tlog2, lacc);
        k_final<<<1, 1, 0, stream>>>(lacc, (float*)d_out);
        return;
    }

    // ---- fallback path (tiny workspace): old per-step kernel loop ----
    float* f_h_f32  = (float*)(ws + 0);          // 2 x [64,512] f32
    float* f_enc0   = (float*)(ws + 262144);
    short* f_h_bf   = (short*)(ws + 393216);     // 2 x [64,512] bf16
    short* f_c_bf   = (short*)(ws + 524288);
    float* f_lacc   = (float*)(ws + 589824);
    unsigned int* f_bar  = (unsigned int*)(ws + 590080);
    unsigned int* f_bar2 = (unsigned int*)(ws + 590208);
    float* f_pm     = (float*)(ws + 590336);
    float* f_ps     = (float*)(ws + 790528);
    float* f_tlog   = (float*)(ws + 990720);
    short* f_encWb  = (short*)(ws + 990976);
    short* f_decWb  = (short*)(ws + 4136704);
    const bool f_tier1 = ws_size >= 7282432;

    k_init<<<1, 64, 0, stream>>>(f_lacc, f_bar, f_bar2);
    if (f_tier1) {
        k_cvt<<<768, 256, 0, stream>>>(enc_Wih, f_encWb, 786432);
        k_cvt<<<768, 256, 0, stream>>>(enc_Whh, f_encWb + 786432, 786432);
        k_cvt<<<768, 256, 0, stream>>>(dec_Wih, f_decWb, 786432);
        k_cvt<<<768, 256, 0, stream>>>(dec_Whh, f_decWb + 786432, 786432);
    }
    k_enc_persist<<<32, 256, 0, stream>>>(
        emb, input_t, f_tier1 ? f_encWb : nullptr, enc_Wih, enc_Whh,
        enc_bih, enc_bhh, f_h_f32, f_h_bf, f_enc0, f_bar);
    for (int td = 0; td < 100; ++td) {
        const float* hi  = f_h_f32 + (td & 1) * 32768;
        const short* hib = f_h_bf  + (td & 1) * 32768;
        float* ho  = f_h_f32 + ((td + 1) & 1) * 32768;
        short* hob = f_h_bf  + ((td + 1) & 1) * 32768;
        k_attncomb<<<64, 256, 0, stream>>>(emb, hi, f_enc0, attn_W, attn_b,
                                           comb_W, comb_b, target_t, td, f_c_bf);
        k_gru1<<<32, 256, 0, stream>>>(f_c_bf, f_tier1 ? f_decWb : nullptr,
                                       dec_Wih, dec_Whh, dec_bih, dec_bhh,
                                       hi, hib, ho, hob);
        k_outloss<<<782, 256, 0, stream>>>(hob, nullptr, out_W,
                                           out_b, target_t + td * 64,
                                           f_pm, f_ps, f_tlog);
        k_lossred<<<64, 256, 0, stream>>>(f_pm, f_ps, f_tlog, f_lacc);
    }
    k_final<<<1, 1, 0, stream>>>(f_lacc, (float*)d_out);
}